// Round 9
// baseline (282.352 us; speedup 1.0000x reference)
//
#include <hip/hip_runtime.h>
#include <math.h>

#define NDIN 128
#define NHID 128
#define NDOUT 64

typedef _Float16 half2_t __attribute__((ext_vector_type(2)));
typedef _Float16 half4_t __attribute__((ext_vector_type(4)));
typedef _Float16 half8_t __attribute__((ext_vector_type(8)));
typedef float    float4v __attribute__((ext_vector_type(4)));

__device__ __forceinline__ float gelu_exact(float x) {
    return 0.5f * x * (1.0f + erff(x * 0.70710678118654752f));
}

// ---------------- prep0: 3x weight transpose+cast + zero done ----------------

__device__ void wtrans_tile(const float* __restrict__ W, _Float16* __restrict__ Wt,
                            int K, int N, int bx, int by) {
    __shared__ float tile[32][33];
    int tx = threadIdx.x & 31, ty = threadIdx.x >> 5;   // ty 0..7
    for (int i = 0; i < 32; i += 8) {
        int k = by * 32 + ty + i, nn = bx * 32 + tx;
        tile[ty + i][tx] = (k < K && nn < N) ? W[(size_t)k * N + nn] : 0.f;
    }
    __syncthreads();
    for (int i = 0; i < 32; i += 8) {
        int nn = bx * 32 + ty + i, k = by * 32 + tx;
        if (nn < N && k < K) Wt[(size_t)nn * K + k] = (_Float16)tile[tx][ty + i];
    }
}

__global__ __launch_bounds__(256) void prep0_kernel(
    const float* __restrict__ W1, _Float16* __restrict__ W1t,
    const float* __restrict__ W2, _Float16* __restrict__ W2t,
    const float* __restrict__ W3, _Float16* __restrict__ W3t,
    int* __restrict__ done) {
    int b = blockIdx.x;
    if (b < 16) {
        wtrans_tile(W1, W1t, NDIN, NHID, b & 3, b >> 2);
    } else if (b < 32) {
        wtrans_tile(W2, W2t, NHID, NHID, (b - 16) & 3, (b - 16) >> 2);
    } else if (b < 40) {
        wtrans_tile(W3, W3t, NHID, NDOUT, (b - 32) & 1, (b - 32) >> 1);
    } else {
        if (threadIdx.x < 64) done[threadIdx.x] = 0;
    }
}

// ---------------- shared GEMM phase: T[64,BN] tile = lds_a[64,128] @ Bt^T --------------
// Global-B (L1-resident 32 KB weight), 17.4 KB LDS.

template <int BN>
__device__ __forceinline__ void gemm_phaseB(
    const _Float16 (*lds_a)[136], const _Float16* __restrict__ Bt,
    _Float16* __restrict__ T, int bm, int M) {
    int tid = threadIdx.x;
    int wave = tid >> 6, lane = tid & 63;
    int m = lane & 15, quad = lane >> 4;
    const int NT = BN / 16;
    float4v acc[NT];
#pragma unroll
    for (int nt = 0; nt < NT; nt++) acc[nt] = (float4v){0.f, 0.f, 0.f, 0.f};
    int arow = (wave << 4) + m;
#pragma unroll
    for (int kc = 0; kc < 128; kc += 32) {
        half8_t a = *(const half8_t*)&lds_a[arow][kc + quad * 8];
#pragma unroll
        for (int nt = 0; nt < NT; nt++) {
            half8_t b = *(const half8_t*)&Bt[(size_t)(nt * 16 + m) * 128 + kc + quad * 8];
            acc[nt] = __builtin_amdgcn_mfma_f32_16x16x32_f16(a, b, acc[nt], 0, 0, 0);
        }
    }
#pragma unroll
    for (int nt = 0; nt < NT; nt++) {
#pragma unroll
        for (int r = 0; r < 4; r++) {
            int grow = bm + (wave << 4) + (quad << 2) + r;
            if (grow < M) T[(size_t)grow * BN + nt * 16 + m] = (_Float16)acc[nt][r];
        }
    }
}

// ---------------- K1: per-block bucket histogram (LDS only!) || gemm1 ------------------
// R8 verdict: 800k return-atomics = 800k 64B fabric line RMWs at ~1.1 TB/s = ~46 us;
// replicas null. This kernel has ZERO global atomics: LDS histogram over 196 buckets
// (bucket = dst>>8), coalesced hist[blk][bucket] write. gemm1 rides along (indep).

__global__ __launch_bounds__(256) void hist_gemm1_kernel(
    const int* __restrict__ dst, int* __restrict__ hist, int E,
    const float* __restrict__ x, const _Float16* __restrict__ W1t,
    _Float16* __restrict__ T, int M, int hblocks) {
    __shared__ _Float16 lds_a[64][136];
    __shared__ int h[256];
    int b = blockIdx.x;
    int tid = threadIdx.x;
    if (b < hblocks) {                          // ---- histogram ----
        h[tid] = 0;
        __syncthreads();
        int e = b * 256 + tid;
        if (e < E) atomicAdd(&h[dst[e] >> 8], 1);     // LDS atomic: cheap
        __syncthreads();
        hist[b * 256 + tid] = h[tid];                 // coalesced
        return;
    }
    // ---- gemm1: stage x (fp32 -> fp16) then MFMA ----
    int bm = (b - hblocks) * 64;
#pragma unroll
    for (int j = 0; j < 8; j++) {
        int c = tid + j * 256;
        int r = c >> 5, col = (c & 31) << 2;
        int grow = bm + r;
        float4 v = make_float4(0.f, 0.f, 0.f, 0.f);
        if (grow < M) v = *(const float4*)(x + (size_t)grow * 128 + col);
        half4_t hh;
        hh[0] = (_Float16)v.x; hh[1] = (_Float16)v.y;
        hh[2] = (_Float16)v.z; hh[3] = (_Float16)v.w;
        *(half4_t*)&lds_a[r][col] = hh;
    }
    __syncthreads();
    gemm_phaseB<128>(lds_a, W1t, T, bm, M);
}

// ---------------- K2: per-bucket scan of hist down the block axis ----------------------
// Block b: exclusive-scan hist[blk][b] over blk (in place), publish bucket total;
// last-arriving block scans the 196 totals -> bbase[]. No spin: only K3 reads bbase.

__global__ __launch_bounds__(1024) void bscan_kernel(
    int* __restrict__ hist, int* __restrict__ btotal, int* __restrict__ bbase,
    int* __restrict__ done, int EB, int nbk) {
    __shared__ int s[1024];
    __shared__ int carry;
    int b = blockIdx.x, t = threadIdx.x;
    if (t == 0) carry = 0;
    __syncthreads();
    for (int c0 = 0; c0 < EB; c0 += 1024) {
        int blk = c0 + t;
        int v = (blk < EB) ? hist[blk * 256 + b] : 0;
        s[t] = v;
        __syncthreads();
        for (int off = 1; off < 1024; off <<= 1) {
            int u = (t >= off) ? s[t - off] : 0;
            __syncthreads();
            s[t] += u;
            __syncthreads();
        }
        if (blk < EB) hist[blk * 256 + b] = carry + (s[t] - v);   // exclusive + carry
        int ctot = s[1023];
        __syncthreads();
        if (t == 0) carry += ctot;
        __syncthreads();
    }
    if (t == 0) {
        atomicExch(&btotal[b], carry);
        __threadfence();
        int old = atomicAdd(&done[0], 1);
        if (old == nbk - 1) {                 // last block: scan bucket totals
            int acc = 0;
            for (int i = 0; i < nbk; i++) {
                int ti = atomicAdd(&btotal[i], 0);   // coherent read
                bbase[i] = acc;
                acc += ti;
            }
            bbase[nbk] = acc;                 // == E
        }
    }
}

// ---------------- K3: scatter edges into bucket-contiguous tmp -------------------------
// pos = bbase[b] + hist[blk][b](exclusive prefix) + LDS-rank. LDS return-atomics only.
// Writes land in 196 contiguous regions -> L3 merges partial lines (tmp is 6.4 MB,
// fully L3-resident).

__global__ __launch_bounds__(256) void scatter_kernel(
    const int* __restrict__ src, const int* __restrict__ dst,
    const int* __restrict__ hist, const int* __restrict__ bbase,
    int2* __restrict__ tmp, int E) {
    __shared__ int rank[256];
    int t = threadIdx.x;
    rank[t] = 0;
    __syncthreads();
    int blk = blockIdx.x;
    int e = blk * 256 + t;
    if (e < E) {
        int d = dst[e];
        int b = d >> 8;
        int lr = atomicAdd(&rank[b], 1);            // LDS
        int pos = bbase[b] + hist[blk * 256 + b] + lr;
        tmp[pos] = make_int2(src[e], d);
    }
}

// ---------------- K4a: per-bucket count + local scan -> rowptr, dinv -------------------
// One block per bucket; bucket's edges are CONTIGUOUS in tmp (coalesced reads).

__global__ __launch_bounds__(1024) void bcsr_a_kernel(
    const int2* __restrict__ tmp, const int* __restrict__ bbase,
    int* __restrict__ rowptr, float* __restrict__ dinv, int N, int E) {
    __shared__ int cnt[256];
    __shared__ int loc[256];
    int b = blockIdx.x, t = threadIdx.x;
    if (t < 256) cnt[t] = 0;
    __syncthreads();
    int base = bbase[b], end = bbase[b + 1];
    for (int i = base + t; i < end; i += 1024)
        atomicAdd(&cnt[tmp[i].y & 255], 1);          // LDS
    __syncthreads();
    if (t < 256) loc[t] = cnt[t];
    __syncthreads();
    for (int off = 1; off < 256; off <<= 1) {
        int u = (t < 256 && t >= off) ? loc[t - off] : 0;
        __syncthreads();
        if (t < 256) loc[t] += u;
        __syncthreads();
    }
    int d0 = b * 256;
    if (t < 256 && d0 + t < N) {
        rowptr[d0 + t] = base + loc[t] - cnt[t];     // exclusive
        dinv[d0 + t] = rsqrtf((float)(cnt[t] + 1));
    }
    if (b == 0 && t == 0) rowptr[N] = E;
}

// ---------------- K4b: per-bucket rank -> adj (src, weight), compact writes ------------
// dinv for the dst side preloaded to LDS (bucket-local); dinv[src] is a random gather
// into a 200 KB L2/L3-resident array. adj writes cover each bucket's contiguous region
// densely -> write-allocate collapses from ~51 MB (old fill) to ~6.4 MB.

__global__ __launch_bounds__(1024) void bcsr_b_kernel(
    const int2* __restrict__ tmp, const int* __restrict__ bbase,
    const int* __restrict__ rowptr, const float* __restrict__ dinv,
    int2* __restrict__ adj, int N) {
    __shared__ int rank[256];
    __shared__ float dloc[256];
    __shared__ int rploc[256];
    int b = blockIdx.x, t = threadIdx.x;
    int d0 = b * 256;
    if (t < 256) {
        rank[t] = 0;
        bool v = (d0 + t < N);
        dloc[t] = v ? dinv[d0 + t] : 0.f;
        rploc[t] = v ? rowptr[d0 + t] : 0;
    }
    __syncthreads();
    int base = bbase[b], end = bbase[b + 1];
    for (int i = base + t; i < end; i += 1024) {
        int2 ed = tmp[i];
        int j = ed.y & 255;
        float w = dinv[ed.x] * dloc[j];              // gather || LDS ops below
        int r = atomicAdd(&rank[j], 1);              // LDS
        adj[rploc[j] + r] = make_int2(ed.x, __float_as_int(w));
    }
}

// ---------------- agg body for one node, F=128 (R4 readlane formulation) ----------------

__device__ __forceinline__ half2_t agg_node128(
    const half2_t* __restrict__ t2, const int* __restrict__ rowptr,
    const int2* __restrict__ adj, const float* __restrict__ dinv,
    const float* __restrict__ bias, int node, int lane) {
    float wself = dinv[node];
    wself *= wself;
    half2_t v = t2[(size_t)node * 64 + lane];
    float accx = wself * (float)v[0], accy = wself * (float)v[1];
    int beg = rowptr[node], end = rowptr[node + 1];
    for (int e0 = beg; e0 < end; e0 += 64) {
        int rem = end - e0;
        int j = 0; float w = 0.f;
        if (lane < rem) {
            int2 ed = adj[e0 + lane];
            j = ed.x; w = __int_as_float(ed.y);
        }
        int cnt = rem < 64 ? rem : 64;
        for (int c = 0; c < cnt; c += 16) {
#pragma unroll
            for (int i = 0; i < 16; i++) {
                int jj = __builtin_amdgcn_readlane(j, c + i);
                float ww = __int_as_float(
                    __builtin_amdgcn_readlane(__float_as_int(w), c + i));
                half2_t u = t2[(size_t)jj * 64 + lane];
                accx += ww * (float)u[0];
                accy += ww * (float)u[1];
            }
        }
    }
    float2 b = ((const float2*)bias)[lane];
    accx = gelu_exact(accx + b.x);
    accy = gelu_exact(accy + b.y);
    half2_t o; o[0] = (_Float16)accx; o[1] = (_Float16)accy;
    return o;
}

// ---------------- fused agg_i -> gemm_{i+1}, 16-row tiles (R3/R7-proven best) ----------
// R8 A/B settled: fused layers beat standalone by ~10 us total; gather ~2.1 TB/s is the
// structural floor in every formulation.

template <int BN>
__global__ __launch_bounds__(256) void agg_gemm16_kernel(
    const _Float16* __restrict__ t, const int* __restrict__ rowptr,
    const int2* __restrict__ adj, const float* __restrict__ dinv,
    const float* __restrict__ bias, const _Float16* __restrict__ Bt,
    _Float16* __restrict__ T, int M) {
    __shared__ _Float16 lds_a[16][136];
    int tid = threadIdx.x;
    int wave = tid >> 6, lane = tid & 63;
    int bm = blockIdx.x * 16;
    const half2_t* t2 = (const half2_t*)t;
#pragma unroll 1
    for (int p = 0; p < 4; p++) {
        int r = (wave << 2) + p;
        int node = bm + r;
        half2_t o;
        o[0] = (_Float16)0.f; o[1] = (_Float16)0.f;
        if (node < M) o = agg_node128(t2, rowptr, adj, dinv, bias, node, lane);
        *(half2_t*)&lds_a[r][lane << 1] = o;   // 4B/lane: conflict-free
    }
    __syncthreads();

    int m = lane & 15, quad = lane >> 4;
    const int NT = BN / 64;                    // fragments per wave: 128->2, 64->1
    float4v acc[NT];
#pragma unroll
    for (int nt = 0; nt < NT; nt++) acc[nt] = (float4v){0.f, 0.f, 0.f, 0.f};
#pragma unroll
    for (int kc = 0; kc < 128; kc += 32) {
        half8_t a = *(const half8_t*)&lds_a[m][kc + quad * 8];
#pragma unroll
        for (int nt = 0; nt < NT; nt++) {
            int col = wave * (BN / 4) + nt * 16 + m;
            half8_t b = *(const half8_t*)&Bt[(size_t)col * 128 + kc + quad * 8];
            acc[nt] = __builtin_amdgcn_mfma_f32_16x16x32_f16(a, b, acc[nt], 0, 0, 0);
        }
    }
#pragma unroll
    for (int nt = 0; nt < NT; nt++) {
#pragma unroll
        for (int r = 0; r < 4; r++) {
            int grow = bm + (quad << 2) + r;
            int col = wave * (BN / 4) + nt * 16 + m;
            if (grow < M) T[(size_t)grow * BN + col] = (_Float16)acc[nt][r];
        }
    }
}

// ---------------- final aggregation (R4 readlane formulation, R0-proven) ---------------

template <int F, bool DOGELU, bool OUTF16>
__global__ __launch_bounds__(256) void agg_kernel(
    const _Float16* __restrict__ t, const int* __restrict__ rowptr,
    const int2* __restrict__ adj, const float* __restrict__ dinv,
    const float* __restrict__ bias, void* __restrict__ outp, int n) {
    int node = (int)((blockIdx.x * blockDim.x + threadIdx.x) >> 6);
    int lane = threadIdx.x & 63;
    if (node >= n) return;   // wave-uniform exit

    float wself = dinv[node];
    wself *= wself;
    int beg = rowptr[node];
    int end = rowptr[node + 1];

    if (F == 128) {
        const half2_t* t2 = (const half2_t*)t;
        half2_t v = t2[(size_t)node * 64 + lane];
        float accx = wself * (float)v[0], accy = wself * (float)v[1];
        for (int e0 = beg; e0 < end; e0 += 64) {
            int rem = end - e0;
            int j = 0; float w = 0.f;
            if (lane < rem) {
                int2 ed = adj[e0 + lane];
                j = ed.x; w = __int_as_float(ed.y);
            }
            int cnt = rem < 64 ? rem : 64;
            for (int c = 0; c < cnt; c += 16) {
#pragma unroll
                for (int i = 0; i < 16; i++) {
                    int jj = __builtin_amdgcn_readlane(j, c + i);
                    float ww = __int_as_float(
                        __builtin_amdgcn_readlane(__float_as_int(w), c + i));
                    half2_t u = t2[(size_t)jj * 64 + lane];
                    accx += ww * (float)u[0];
                    accy += ww * (float)u[1];
                }
            }
        }
        float2 b = ((const float2*)bias)[lane];
        accx += b.x; accy += b.y;
        if (DOGELU) { accx = gelu_exact(accx); accy = gelu_exact(accy); }
        if (OUTF16) {
            half2_t o; o[0] = (_Float16)accx; o[1] = (_Float16)accy;
            ((half2_t*)outp)[(size_t)node * 64 + lane] = o;
        } else {
            float2 o; o.x = accx; o.y = accy;
            ((float2*)outp)[(size_t)node * 64 + lane] = o;
        }
    } else {  // F == 64
        float acc = wself * (float)t[(size_t)node * 64 + lane];
        for (int e0 = beg; e0 < end; e0 += 64) {
            int rem = end - e0;
            int j = 0; float w = 0.f;
            if (lane < rem) {
                int2 ed = adj[e0 + lane];
                j = ed.x; w = __int_as_float(ed.y);
            }
            int cnt = rem < 64 ? rem : 64;
            for (int c = 0; c < cnt; c += 16) {
#pragma unroll
                for (int i = 0; i < 16; i++) {
                    int jj = __builtin_amdgcn_readlane(j, c + i);
                    float ww = __int_as_float(
                        __builtin_amdgcn_readlane(__float_as_int(w), c + i));
                    acc += ww * (float)t[(size_t)jj * 64 + lane];
                }
            }
        }
        acc += bias[lane];
        if (DOGELU) acc = gelu_exact(acc);
        if (OUTF16) ((_Float16*)outp)[(size_t)node * 64 + lane] = (_Float16)acc;
        else        ((float*)outp)[(size_t)node * 64 + lane] = acc;
    }
}

// ---------------- launch ----------------

extern "C" void kernel_launch(void* const* d_in, const int* in_sizes, int n_in,
                              void* d_out, int out_size, void* d_ws, size_t ws_size,
                              hipStream_t stream) {
    const float* x  = (const float*)d_in[0];
    const int* edge = (const int*)d_in[1];
    const float* W1 = (const float*)d_in[2];
    const float* b1 = (const float*)d_in[3];
    const float* W2 = (const float*)d_in[4];
    const float* b2 = (const float*)d_in[5];
    const float* W3 = (const float*)d_in[6];
    const float* b3 = (const float*)d_in[7];
    float* out = (float*)d_out;

    const int N = in_sizes[0] / NDIN;       // 50000
    const int E = in_sizes[1] / 2;          // 800000
    const int* src = edge;
    const int* dst = edge + E;
    const int NBK = (N + 255) >> 8;         // 196 buckets (dst>>8)
    const int EB  = (E + 255) / 256;        // 3125 edge blocks

    // workspace carve-out (256B aligned)
    char* p = (char*)d_ws;
    auto alloc = [&](size_t bytes) {
        char* q = p;
        p += (bytes + 255) & ~(size_t)255;
        return q;
    };
    int*       hist     = (int*)alloc((size_t)EB * 256 * 4);     // 3.2 MB
    int*       btotal   = (int*)alloc((size_t)NBK * 4);
    int*       bbase    = (int*)alloc((size_t)(NBK + 1) * 4);
    int*       done     = (int*)alloc(256);
    int*       rowptr   = (int*)alloc((size_t)(N + 1) * 4);
    float*     dinv     = (float*)alloc((size_t)N * 4);
    int2*      tmp      = (int2*)alloc((size_t)E * 8);
    int2*      adj      = (int2*)alloc((size_t)E * 8);
    _Float16*  W1t      = (_Float16*)alloc((size_t)NHID * NDIN * 2);
    _Float16*  W2t      = (_Float16*)alloc((size_t)NHID * NHID * 2);
    _Float16*  W3t      = (_Float16*)alloc((size_t)NDOUT * NHID * 2);
    _Float16*  tbuf     = (_Float16*)alloc((size_t)N * NHID * 2);
    _Float16*  hbuf     = (_Float16*)alloc((size_t)N * NHID * 2);

    dim3 blk(256);
    dim3 blk1k(1024);
    int mtiles = (N + 63) / 64;             // 782
    int ntiles16 = (N + 15) / 16;           // 3125
    int agg_blocks = (N + 3) / 4;           // 12500

    // 1. weight transpose+cast + zero done
    prep0_kernel<<<41, blk, 0, stream>>>(W1, W1t, W2, W2t, W3, W3t, done);
    // 2. bucket histogram (LDS-only) || gemm1
    hist_gemm1_kernel<<<EB + mtiles, blk, 0, stream>>>(dst, hist, E, x, W1t,
                                                       tbuf, N, EB);
    // 3. per-bucket scan of hist + bucket bases (last-block)
    bscan_kernel<<<NBK, blk1k, 0, stream>>>(hist, btotal, bbase, done, EB, NBK);
    // 4. scatter edges to bucket-contiguous tmp (LDS ranks only)
    scatter_kernel<<<EB, blk, 0, stream>>>(src, dst, hist, bbase, tmp, E);
    // 5. per-bucket count/scan -> rowptr, dinv
    bcsr_a_kernel<<<NBK, blk1k, 0, stream>>>(tmp, bbase, rowptr, dinv, N, E);
    // 6. per-bucket ranks -> adj (src, weight), compact writes
    bcsr_b_kernel<<<NBK, blk1k, 0, stream>>>(tmp, bbase, rowptr, dinv, adj, N);
    // 7. layer 2 fused: agg1 (gelu,b1) + gemm2 -> hbuf
    agg_gemm16_kernel<128><<<ntiles16, blk, 0, stream>>>(tbuf, rowptr, adj, dinv, b1,
                                                         W2t, hbuf, N);
    // 8. layer 3 fused: agg2 (gelu,b2) + gemm3 -> tbuf (N x 64 fp16)
    agg_gemm16_kernel<64><<<ntiles16, blk, 0, stream>>>(hbuf, rowptr, adj, dinv, b2,
                                                        W3t, tbuf, N);
    // 9. final agg (no gelu, fp32 out)
    agg_kernel<64, false, false><<<agg_blocks, blk, 0, stream>>>(tbuf, rowptr, adj,
                                                                 dinv, b3, out, N);
}

// Round 10
// 268.409 us; speedup vs baseline: 1.0519x; 1.0519x over previous
//
#include <hip/hip_runtime.h>
#include <math.h>

#define NDIN 128
#define NHID 128
#define NDOUT 64
#define CHUNKS 512   // fat histogram/scatter chunks (R9 bscan fix: scan axis 3125 -> 512)

typedef _Float16 half2_t __attribute__((ext_vector_type(2)));
typedef _Float16 half4_t __attribute__((ext_vector_type(4)));
typedef _Float16 half8_t __attribute__((ext_vector_type(8)));
typedef float    float4v __attribute__((ext_vector_type(4)));

__device__ __forceinline__ float gelu_exact(float x) {
    return 0.5f * x * (1.0f + erff(x * 0.70710678118654752f));
}

// ---------------- prep0: 3x weight transpose+cast + zero done ----------------

__device__ void wtrans_tile(const float* __restrict__ W, _Float16* __restrict__ Wt,
                            int K, int N, int bx, int by) {
    __shared__ float tile[32][33];
    int tx = threadIdx.x & 31, ty = threadIdx.x >> 5;   // ty 0..7
    for (int i = 0; i < 32; i += 8) {
        int k = by * 32 + ty + i, nn = bx * 32 + tx;
        tile[ty + i][tx] = (k < K && nn < N) ? W[(size_t)k * N + nn] : 0.f;
    }
    __syncthreads();
    for (int i = 0; i < 32; i += 8) {
        int nn = bx * 32 + ty + i, k = by * 32 + tx;
        if (nn < N && k < K) Wt[(size_t)nn * K + k] = (_Float16)tile[tx][ty + i];
    }
}

__global__ __launch_bounds__(256) void prep0_kernel(
    const float* __restrict__ W1, _Float16* __restrict__ W1t,
    const float* __restrict__ W2, _Float16* __restrict__ W2t,
    const float* __restrict__ W3, _Float16* __restrict__ W3t,
    int* __restrict__ done) {
    int b = blockIdx.x;
    if (b < 16) {
        wtrans_tile(W1, W1t, NDIN, NHID, b & 3, b >> 2);
    } else if (b < 32) {
        wtrans_tile(W2, W2t, NHID, NHID, (b - 16) & 3, (b - 16) >> 2);
    } else if (b < 40) {
        wtrans_tile(W3, W3t, NHID, NDOUT, (b - 32) & 1, (b - 32) >> 1);
    } else {
        if (threadIdx.x < 64) done[threadIdx.x] = 0;
    }
}

// ---------------- shared GEMM phase: T[64,BN] tile = lds_a[64,128] @ Bt^T --------------

template <int BN>
__device__ __forceinline__ void gemm_phaseB(
    const _Float16 (*lds_a)[136], const _Float16* __restrict__ Bt,
    _Float16* __restrict__ T, int bm, int M) {
    int tid = threadIdx.x;
    int wave = tid >> 6, lane = tid & 63;
    int m = lane & 15, quad = lane >> 4;
    const int NT = BN / 16;
    float4v acc[NT];
#pragma unroll
    for (int nt = 0; nt < NT; nt++) acc[nt] = (float4v){0.f, 0.f, 0.f, 0.f};
    int arow = (wave << 4) + m;
#pragma unroll
    for (int kc = 0; kc < 128; kc += 32) {
        half8_t a = *(const half8_t*)&lds_a[arow][kc + quad * 8];
#pragma unroll
        for (int nt = 0; nt < NT; nt++) {
            half8_t b = *(const half8_t*)&Bt[(size_t)(nt * 16 + m) * 128 + kc + quad * 8];
            acc[nt] = __builtin_amdgcn_mfma_f32_16x16x32_f16(a, b, acc[nt], 0, 0, 0);
        }
    }
#pragma unroll
    for (int nt = 0; nt < NT; nt++) {
#pragma unroll
        for (int r = 0; r < 4; r++) {
            int grow = bm + (wave << 4) + (quad << 2) + r;
            if (grow < M) T[(size_t)grow * BN + nt * 16 + m] = (_Float16)acc[nt][r];
        }
    }
}

// ---------------- K1: fat-chunk bucket histogram (LDS only) || gemm1 -------------------
// CHUNKS fat blocks, each grid-strides its ~1563-edge chunk. Zero global atomics.
// hist row write coalesced. hist = CHUNKS x 256 = 512 KB (L2-resident for bscan).

__global__ __launch_bounds__(256) void hist_gemm1_kernel(
    const int* __restrict__ dst, int* __restrict__ hist, int E, int cs,
    const float* __restrict__ x, const _Float16* __restrict__ W1t,
    _Float16* __restrict__ T, int M, int hblocks) {
    __shared__ _Float16 lds_a[64][136];
    __shared__ int h[256];
    int b = blockIdx.x;
    int tid = threadIdx.x;
    if (b < hblocks) {                          // ---- fat histogram ----
        h[tid] = 0;
        __syncthreads();
        int beg = b * cs, end = beg + cs;
        if (end > E) end = E;
        for (int e = beg + tid; e < end; e += 256)
            atomicAdd(&h[dst[e] >> 8], 1);            // LDS atomic: cheap
        __syncthreads();
        hist[b * 256 + tid] = h[tid];                 // coalesced
        return;
    }
    // ---- gemm1: stage x (fp32 -> fp16) then MFMA ----
    int bm = (b - hblocks) * 64;
#pragma unroll
    for (int j = 0; j < 8; j++) {
        int c = tid + j * 256;
        int r = c >> 5, col = (c & 31) << 2;
        int grow = bm + r;
        float4 v = make_float4(0.f, 0.f, 0.f, 0.f);
        if (grow < M) v = *(const float4*)(x + (size_t)grow * 128 + col);
        half4_t hh;
        hh[0] = (_Float16)v.x; hh[1] = (_Float16)v.y;
        hh[2] = (_Float16)v.z; hh[3] = (_Float16)v.w;
        *(half4_t*)&lds_a[r][col] = hh;
    }
    __syncthreads();
    gemm_phaseB<128>(lds_a, W1t, T, bm, M);
}

// ---------------- K2: per-bucket scan of hist down the chunk axis ----------------------
// R9's 54 us bottleneck fixed by data-size: 512 chunks x 4B = strided reads but only
// 512 KB total, L2-resident. Block b scans hist[c][b] over c (in place, exclusive);
// last-arriving block scans the 196 totals -> bbase[]. Only K3 reads bbase.

__global__ __launch_bounds__(1024) void bscan_kernel(
    int* __restrict__ hist, int* __restrict__ btotal, int* __restrict__ bbase,
    int* __restrict__ done, int EB, int nbk) {
    __shared__ int s[1024];
    __shared__ int carry;
    int b = blockIdx.x, t = threadIdx.x;
    if (t == 0) carry = 0;
    __syncthreads();
    for (int c0 = 0; c0 < EB; c0 += 1024) {
        int blk = c0 + t;
        int v = (blk < EB) ? hist[blk * 256 + b] : 0;
        s[t] = v;
        __syncthreads();
        for (int off = 1; off < 1024; off <<= 1) {
            int u = (t >= off) ? s[t - off] : 0;
            __syncthreads();
            s[t] += u;
            __syncthreads();
        }
        if (blk < EB) hist[blk * 256 + b] = carry + (s[t] - v);   // exclusive + carry
        int ctot = s[1023];
        __syncthreads();
        if (t == 0) carry += ctot;
        __syncthreads();
    }
    if (t == 0) {
        atomicExch(&btotal[b], carry);
        __threadfence();
        int old = atomicAdd(&done[0], 1);
        if (old == nbk - 1) {                 // last block: scan bucket totals
            int acc = 0;
            for (int i = 0; i < nbk; i++) {
                int ti = atomicAdd(&btotal[i], 0);   // coherent read
                bbase[i] = acc;
                acc += ti;
            }
            bbase[nbk] = acc;                 // == E
        }
    }
}

// ---------------- K3: fat-chunk scatter into bucket-contiguous tmp ---------------------
// Block c: load its hist row + bbase into LDS (coalesced, once), then grid-stride its
// chunk: LDS rank atomics only; writes land in 196 contiguous regions (tmp = 6.4 MB,
// L2/L3-resident). Rank uniqueness per (chunk,bucket); hist prefix makes chunks disjoint.

__global__ __launch_bounds__(256) void scatter_kernel(
    const int* __restrict__ src, const int* __restrict__ dst,
    const int* __restrict__ hist, const int* __restrict__ bbase,
    int2* __restrict__ tmp, int E, int cs, int nbk) {
    __shared__ int rank[256];
    __shared__ int base[256];
    int c = blockIdx.x, t = threadIdx.x;
    rank[t] = 0;
    base[t] = (t < nbk) ? (bbase[t] + hist[c * 256 + t]) : 0;
    __syncthreads();
    int beg = c * cs, end = beg + cs;
    if (end > E) end = E;
    for (int e = beg + t; e < end; e += 256) {
        int d = dst[e];
        int b = d >> 8;
        int lr = atomicAdd(&rank[b], 1);            // LDS
        tmp[base[b] + lr] = make_int2(src[e], d);
    }
}

// ---------------- K4a: per-bucket count + local scan -> rowptr, dinv -------------------

__global__ __launch_bounds__(1024) void bcsr_a_kernel(
    const int2* __restrict__ tmp, const int* __restrict__ bbase,
    int* __restrict__ rowptr, float* __restrict__ dinv, int N, int E) {
    __shared__ int cnt[256];
    __shared__ int loc[256];
    int b = blockIdx.x, t = threadIdx.x;
    if (t < 256) cnt[t] = 0;
    __syncthreads();
    int base = bbase[b], end = bbase[b + 1];
    for (int i = base + t; i < end; i += 1024)
        atomicAdd(&cnt[tmp[i].y & 255], 1);          // LDS
    __syncthreads();
    if (t < 256) loc[t] = cnt[t];
    __syncthreads();
    for (int off = 1; off < 256; off <<= 1) {
        int u = (t < 256 && t >= off) ? loc[t - off] : 0;
        __syncthreads();
        if (t < 256) loc[t] += u;
        __syncthreads();
    }
    int d0 = b * 256;
    if (t < 256 && d0 + t < N) {
        rowptr[d0 + t] = base + loc[t] - cnt[t];     // exclusive
        dinv[d0 + t] = rsqrtf((float)(cnt[t] + 1));
    }
    if (b == 0 && t == 0) rowptr[N] = E;
}

// ---------------- K4b: per-bucket rank -> adj (src, weight), compact writes ------------

__global__ __launch_bounds__(1024) void bcsr_b_kernel(
    const int2* __restrict__ tmp, const int* __restrict__ bbase,
    const int* __restrict__ rowptr, const float* __restrict__ dinv,
    int2* __restrict__ adj, int N) {
    __shared__ int rank[256];
    __shared__ float dloc[256];
    __shared__ int rploc[256];
    int b = blockIdx.x, t = threadIdx.x;
    int d0 = b * 256;
    if (t < 256) {
        rank[t] = 0;
        bool v = (d0 + t < N);
        dloc[t] = v ? dinv[d0 + t] : 0.f;
        rploc[t] = v ? rowptr[d0 + t] : 0;
    }
    __syncthreads();
    int base = bbase[b], end = bbase[b + 1];
    for (int i = base + t; i < end; i += 1024) {
        int2 ed = tmp[i];
        int j = ed.y & 255;
        float w = dinv[ed.x] * dloc[j];              // gather || LDS ops below
        int r = atomicAdd(&rank[j], 1);              // LDS
        adj[rploc[j] + r] = make_int2(ed.x, __float_as_int(w));
    }
}

// ---------------- agg body for one node, F=128 (R4 readlane formulation) ----------------

__device__ __forceinline__ half2_t agg_node128(
    const half2_t* __restrict__ t2, const int* __restrict__ rowptr,
    const int2* __restrict__ adj, const float* __restrict__ dinv,
    const float* __restrict__ bias, int node, int lane) {
    float wself = dinv[node];
    wself *= wself;
    half2_t v = t2[(size_t)node * 64 + lane];
    float accx = wself * (float)v[0], accy = wself * (float)v[1];
    int beg = rowptr[node], end = rowptr[node + 1];
    for (int e0 = beg; e0 < end; e0 += 64) {
        int rem = end - e0;
        int j = 0; float w = 0.f;
        if (lane < rem) {
            int2 ed = adj[e0 + lane];
            j = ed.x; w = __int_as_float(ed.y);
        }
        int cnt = rem < 64 ? rem : 64;
        for (int c = 0; c < cnt; c += 16) {
#pragma unroll
            for (int i = 0; i < 16; i++) {
                int jj = __builtin_amdgcn_readlane(j, c + i);
                float ww = __int_as_float(
                    __builtin_amdgcn_readlane(__float_as_int(w), c + i));
                half2_t u = t2[(size_t)jj * 64 + lane];
                accx += ww * (float)u[0];
                accy += ww * (float)u[1];
            }
        }
    }
    float2 b = ((const float2*)bias)[lane];
    accx = gelu_exact(accx + b.x);
    accy = gelu_exact(accy + b.y);
    half2_t o; o[0] = (_Float16)accx; o[1] = (_Float16)accy;
    return o;
}

// ---------------- fused agg_i -> gemm_{i+1}, 16-row tiles (R3/R7-proven best) ----------

template <int BN>
__global__ __launch_bounds__(256) void agg_gemm16_kernel(
    const _Float16* __restrict__ t, const int* __restrict__ rowptr,
    const int2* __restrict__ adj, const float* __restrict__ dinv,
    const float* __restrict__ bias, const _Float16* __restrict__ Bt,
    _Float16* __restrict__ T, int M) {
    __shared__ _Float16 lds_a[16][136];
    int tid = threadIdx.x;
    int wave = tid >> 6, lane = tid & 63;
    int bm = blockIdx.x * 16;
    const half2_t* t2 = (const half2_t*)t;
#pragma unroll 1
    for (int p = 0; p < 4; p++) {
        int r = (wave << 2) + p;
        int node = bm + r;
        half2_t o;
        o[0] = (_Float16)0.f; o[1] = (_Float16)0.f;
        if (node < M) o = agg_node128(t2, rowptr, adj, dinv, bias, node, lane);
        *(half2_t*)&lds_a[r][lane << 1] = o;   // 4B/lane: conflict-free
    }
    __syncthreads();

    int m = lane & 15, quad = lane >> 4;
    const int NT = BN / 64;                    // fragments per wave: 128->2, 64->1
    float4v acc[NT];
#pragma unroll
    for (int nt = 0; nt < NT; nt++) acc[nt] = (float4v){0.f, 0.f, 0.f, 0.f};
#pragma unroll
    for (int kc = 0; kc < 128; kc += 32) {
        half8_t a = *(const half8_t*)&lds_a[m][kc + quad * 8];
#pragma unroll
        for (int nt = 0; nt < NT; nt++) {
            int col = wave * (BN / 4) + nt * 16 + m;
            half8_t b = *(const half8_t*)&Bt[(size_t)col * 128 + kc + quad * 8];
            acc[nt] = __builtin_amdgcn_mfma_f32_16x16x32_f16(a, b, acc[nt], 0, 0, 0);
        }
    }
#pragma unroll
    for (int nt = 0; nt < NT; nt++) {
#pragma unroll
        for (int r = 0; r < 4; r++) {
            int grow = bm + (quad << 2) + r;
            int col = wave * (BN / 4) + nt * 16 + m;
            if (grow < M) T[(size_t)grow * BN + col] = (_Float16)acc[nt][r];
        }
    }
}

// ---------------- final aggregation (R4 readlane formulation, R0-proven) ---------------

template <int F, bool DOGELU, bool OUTF16>
__global__ __launch_bounds__(256) void agg_kernel(
    const _Float16* __restrict__ t, const int* __restrict__ rowptr,
    const int2* __restrict__ adj, const float* __restrict__ dinv,
    const float* __restrict__ bias, void* __restrict__ outp, int n) {
    int node = (int)((blockIdx.x * blockDim.x + threadIdx.x) >> 6);
    int lane = threadIdx.x & 63;
    if (node >= n) return;   // wave-uniform exit

    float wself = dinv[node];
    wself *= wself;
    int beg = rowptr[node];
    int end = rowptr[node + 1];

    if (F == 128) {
        const half2_t* t2 = (const half2_t*)t;
        half2_t v = t2[(size_t)node * 64 + lane];
        float accx = wself * (float)v[0], accy = wself * (float)v[1];
        for (int e0 = beg; e0 < end; e0 += 64) {
            int rem = end - e0;
            int j = 0; float w = 0.f;
            if (lane < rem) {
                int2 ed = adj[e0 + lane];
                j = ed.x; w = __int_as_float(ed.y);
            }
            int cnt = rem < 64 ? rem : 64;
            for (int c = 0; c < cnt; c += 16) {
#pragma unroll
                for (int i = 0; i < 16; i++) {
                    int jj = __builtin_amdgcn_readlane(j, c + i);
                    float ww = __int_as_float(
                        __builtin_amdgcn_readlane(__float_as_int(w), c + i));
                    half2_t u = t2[(size_t)jj * 64 + lane];
                    accx += ww * (float)u[0];
                    accy += ww * (float)u[1];
                }
            }
        }
        float2 b = ((const float2*)bias)[lane];
        accx += b.x; accy += b.y;
        if (DOGELU) { accx = gelu_exact(accx); accy = gelu_exact(accy); }
        if (OUTF16) {
            half2_t o; o[0] = (_Float16)accx; o[1] = (_Float16)accy;
            ((half2_t*)outp)[(size_t)node * 64 + lane] = o;
        } else {
            float2 o; o.x = accx; o.y = accy;
            ((float2*)outp)[(size_t)node * 64 + lane] = o;
        }
    } else {  // F == 64
        float acc = wself * (float)t[(size_t)node * 64 + lane];
        for (int e0 = beg; e0 < end; e0 += 64) {
            int rem = end - e0;
            int j = 0; float w = 0.f;
            if (lane < rem) {
                int2 ed = adj[e0 + lane];
                j = ed.x; w = __int_as_float(ed.y);
            }
            int cnt = rem < 64 ? rem : 64;
            for (int c = 0; c < cnt; c += 16) {
#pragma unroll
                for (int i = 0; i < 16; i++) {
                    int jj = __builtin_amdgcn_readlane(j, c + i);
                    float ww = __int_as_float(
                        __builtin_amdgcn_readlane(__float_as_int(w), c + i));
                    acc += ww * (float)t[(size_t)jj * 64 + lane];
                }
            }
        }
        acc += bias[lane];
        if (DOGELU) acc = gelu_exact(acc);
        if (OUTF16) ((_Float16*)outp)[(size_t)node * 64 + lane] = (_Float16)acc;
        else        ((float*)outp)[(size_t)node * 64 + lane] = acc;
    }
}

// ---------------- launch ----------------

extern "C" void kernel_launch(void* const* d_in, const int* in_sizes, int n_in,
                              void* d_out, int out_size, void* d_ws, size_t ws_size,
                              hipStream_t stream) {
    const float* x  = (const float*)d_in[0];
    const int* edge = (const int*)d_in[1];
    const float* W1 = (const float*)d_in[2];
    const float* b1 = (const float*)d_in[3];
    const float* W2 = (const float*)d_in[4];
    const float* b2 = (const float*)d_in[5];
    const float* W3 = (const float*)d_in[6];
    const float* b3 = (const float*)d_in[7];
    float* out = (float*)d_out;

    const int N = in_sizes[0] / NDIN;       // 50000
    const int E = in_sizes[1] / 2;          // 800000
    const int* src = edge;
    const int* dst = edge + E;
    const int NBK = (N + 255) >> 8;         // 196 buckets (dst>>8)
    const int CH  = CHUNKS;                 // 512 fat chunks
    const int CS  = (E + CH - 1) / CH;      // 1563 edges per chunk

    // workspace carve-out (256B aligned)
    char* p = (char*)d_ws;
    auto alloc = [&](size_t bytes) {
        char* q = p;
        p += (bytes + 255) & ~(size_t)255;
        return q;
    };
    int*       hist     = (int*)alloc((size_t)CH * 256 * 4);     // 512 KB
    int*       btotal   = (int*)alloc((size_t)NBK * 4);
    int*       bbase    = (int*)alloc((size_t)256 * 4);
    int*       done     = (int*)alloc(256);
    int*       rowptr   = (int*)alloc((size_t)(N + 1) * 4);
    float*     dinv     = (float*)alloc((size_t)N * 4);
    int2*      tmp      = (int2*)alloc((size_t)E * 8);
    int2*      adj      = (int2*)alloc((size_t)E * 8);
    _Float16*  W1t      = (_Float16*)alloc((size_t)NHID * NDIN * 2);
    _Float16*  W2t      = (_Float16*)alloc((size_t)NHID * NHID * 2);
    _Float16*  W3t      = (_Float16*)alloc((size_t)NDOUT * NHID * 2);
    _Float16*  tbuf     = (_Float16*)alloc((size_t)N * NHID * 2);
    _Float16*  hbuf     = (_Float16*)alloc((size_t)N * NHID * 2);

    dim3 blk(256);
    dim3 blk1k(1024);
    int mtiles = (N + 63) / 64;             // 782
    int ntiles16 = (N + 15) / 16;           // 3125
    int agg_blocks = (N + 3) / 4;           // 12500

    // 1. weight transpose+cast + zero done
    prep0_kernel<<<41, blk, 0, stream>>>(W1, W1t, W2, W2t, W3, W3t, done);
    // 2. fat-chunk histogram (LDS-only) || gemm1
    hist_gemm1_kernel<<<CH + mtiles, blk, 0, stream>>>(dst, hist, E, CS, x, W1t,
                                                       tbuf, N, CH);
    // 3. per-bucket scan of hist (512 KB, L2) + bucket bases (last-block)
    bscan_kernel<<<NBK, blk1k, 0, stream>>>(hist, btotal, bbase, done, CH, NBK);
    // 4. fat-chunk scatter to bucket-contiguous tmp (LDS ranks only)
    scatter_kernel<<<CH, blk, 0, stream>>>(src, dst, hist, bbase, tmp, E, CS, NBK);
    // 5. per-bucket count/scan -> rowptr, dinv
    bcsr_a_kernel<<<NBK, blk1k, 0, stream>>>(tmp, bbase, rowptr, dinv, N, E);
    // 6. per-bucket ranks -> adj (src, weight), compact writes
    bcsr_b_kernel<<<NBK, blk1k, 0, stream>>>(tmp, bbase, rowptr, dinv, adj, N);
    // 7. layer 2 fused: agg1 (gelu,b1) + gemm2 -> hbuf
    agg_gemm16_kernel<128><<<ntiles16, blk, 0, stream>>>(tbuf, rowptr, adj, dinv, b1,
                                                         W2t, hbuf, N);
    // 8. layer 3 fused: agg2 (gelu,b2) + gemm3 -> tbuf (N x 64 fp16)
    agg_gemm16_kernel<64><<<ntiles16, blk, 0, stream>>>(hbuf, rowptr, adj, dinv, b2,
                                                        W3t, tbuf, N);
    // 9. final agg (no gelu, fp32 out)
    agg_kernel<64, false, false><<<agg_blocks, blk, 0, stream>>>(tbuf, rowptr, adj,
                                                                 dinv, b3, out, N);
}